// Round 8
// baseline (147.435 us; speedup 1.0000x reference)
//
#include <hip/hip_runtime.h>

#define N2 128
#define MM 16384
#define START 6
#define CB 16        // columns per block -> 1024 blocks -> 4 blocks/CU
#define BT 256       // 4 waves; shares/quarters are 16-lane groups

__global__ __launch_bounds__(BT, 4) void npi_fused(
    const float* __restrict__ rt, const float* __restrict__ dgt,
    const float* __restrict__ si, const float* __restrict__ f,
    const float* __restrict__ seed, float* __restrict__ out)
{
    __shared__ float predT[132 * CB];   // [row][col], rows 128..131 zero
    __shared__ float funion[152 * CB];  // phase1: part[0,1024)+hrow[1024,1280); phase2: fTd[16+d][col]
    __shared__ float si_s[N2];
    __shared__ float lred[4];

    const int t = threadIdx.x;
    const int c = t & 15;          // column
    const int s = (t >> 4) & 1;
    const int h = (t >> 5) & 1;
    const int w = t >> 6;          // wave
    const int q = (h << 1) | s;    // quarter / row-group within wave
    const int g = (h << 3) | (w << 1) | s;   // phase-1 share: xor16<->s, xor32<->h
    const int m = blockIdx.x * CB + c;

    // f -> registers; loads stream under all of phase 1
    float fregs[8];
#pragma unroll
    for (int r = 0; r < 8; ++r)
        fregs[r] = f[((r << 4) + (t >> 4)) * MM + m];

    if (t < N2) si_s[t] = si[t];
    if (t < 64) predT[(128 + (t >> 4)) * CB + (t & 15)] = 0.f;  // pad rows

    float sd[START];
#pragma unroll
    for (int k = 0; k < START; ++k) sd[k] = seed[k * MM + m];
    float rtv[16];
#pragma unroll
    for (int k = 0; k < 16; ++k) rtv[k] = rt[k * MM + m];

    __syncthreads();

    float sr[16];
#pragma unroll
    for (int k = 1; k < 16; ++k) sr[k] = si_s[k];

    // ---- phase 1, chunk 0: short-chain triangle from seeds (redundant) ----
    {
        float p_[16], v[16];
#pragma unroll
        for (int k = 0; k < 16; ++k) p_[k] = 0.f;
#pragma unroll
        for (int k = 0; k < 16; ++k) {
            float vk = (k < START) ? sd[k] : rtv[k] * (p_[k] + sr[1] * v[k - 1]);
            v[k] = vk;
#pragma unroll
            for (int k2 = k + 2; k2 < 16; ++k2)
                p_[k2] += sr[k2 - k] * vk;
        }
        const int row = (w << 2) + q;         // each lane writes exactly 1 row
        predT[row * CB + c] = v[row];
    }
    __syncthreads();

    // ---- phase 1, chunks b = 1..7: 16 equal j-shares of b each ----
    for (int b = 1; b < 8; ++b) {
        const int i0 = b << 4;
#pragma unroll
        for (int k = 0; k < 16; ++k)
            rtv[k] = rt[(i0 + k) * MM + m];   // prefetch for triangle

        const int jtop = b * (g + 1) - 1;     // share j in [b*g, b*(g+1))
        const int base = i0 - jtop;           // >= 1
        float c16[16];
#pragma unroll
        for (int e = 0; e < 16; ++e) c16[e] = si_s[base + e];
        float acc[16];
#pragma unroll
        for (int k = 0; k < 16; ++k) acc[k] = 0.f;
#pragma unroll
        for (int u = 0; u < 7; ++u) {
            if (u < b) {                      // uniform guard
                float pv = predT[(jtop - u) * CB + c];
#pragma unroll
                for (int k = 0; k < 16; ++k)
                    acc[k] += pv * c16[(u + k) & 15];
                if (u + 1 < b) c16[u & 15] = si_s[base + 16 + u];  // <= 127
            }
        }
#pragma unroll
        for (int k = 0; k < 16; ++k) {        // fold 4 in-wave shares (free)
            acc[k] += __shfl_xor(acc[k], 16, 64);
            acc[k] += __shfl_xor(acc[k], 32, 64);
        }
        if ((t & 48) == 0) {                  // one 16-lane group per wave writes
#pragma unroll
            for (int k = 0; k < 16; ++k)
                funion[(w << 8) + (k << 4) + c] = acc[k];
        }
        __syncthreads();

        // stage B: 256 threads == 16k x 16c, one element each (4 reads)
        funion[1024 + t] = funion[t] + funion[256 + t]
                         + funion[512 + t] + funion[768 + t];
        __syncthreads();

        // short-chain triangle (redundant per lane; keeps all SIMDs issuing)
        {
            float p_[16], v[16];
#pragma unroll
            for (int k = 0; k < 16; ++k)
                p_[k] = funion[1024 + (k << 4) + c];   // broadcast reads
#pragma unroll
            for (int k = 0; k < 16; ++k) {
                float vk = (k == 0) ? (rtv[0] * p_[0])
                                    : rtv[k] * (p_[k] + sr[1] * v[k - 1]);
                v[k] = vk;
#pragma unroll
                for (int k2 = k + 2; k2 < 16; ++k2)
                    p_[k2] += sr[k2 - k] * vk;
            }
            const int row = (w << 2) + q;
            predT[(i0 + row) * CB + c] = v[row];
        }
        __syncthreads();
    }

    // ---- stage f -> fTd (funion row 16+d); zero pads ----
    funion[t] = 0.f;                          // rows 0..15 (d = -16..-1)
    if (t < 128) funion[2304 + t] = 0.f;      // rows 144..151 (d = 128..135)
#pragma unroll
    for (int r = 0; r < 8; ++r) {
        int d = (r << 4) + (t >> 4);
        funion[(16 + d) * CB + c] = (d < 2) ? 0.f : fregs[r];
    }
    __syncthreads();

    // ---- phase 2: deaths conv + MSE; wave-uniform chunks, quarter j-split ----
    float lsum = 0.f;
    if (w == 0) {                             // rows 0..5 special
        float dv = dgt[q * MM + m];
        float e0 = (q == 0) ? (1e-9f - dv) : dv;
        lsum += e0 * e0;
        if (q < 2) {
            float d2 = dgt[(4 + q) * MM + m];
            lsum += d2 * d2;
        }
    }

#pragma unroll
    for (int pass = 0; pass < 2; ++pass) {
        const int n = pass ? (7 - w) : w;     // chunk, wave-uniform
        const int i0 = START + (n << 4);
        const int Q = 5 + (n << 2);           // quarter size, wave-uniform
        const int jtop = (q + 1) * Q - 1;     // this quarter's top j
        const int bidx = 16 + i0 - jtop;      // fTd ring base row (>= 3)

        float dgv[4];
#pragma unroll
        for (int r = 0; r < 4; ++r) {
            int i = i0 + (q << 2) + r;
            dgv[r] = (i < N2) ? dgt[i * MM + m] : 0.f;
        }

        float cf[16];
#pragma unroll
        for (int e = 0; e < 16; ++e) cf[e] = funion[(bidx + e) * CB + c];
        float acc[16];
#pragma unroll
        for (int k = 0; k < 16; ++k) acc[k] = 0.f;

        for (int sb = 0; sb < Q; sb += 16) {
#pragma unroll
            for (int u = 0; u < 16; ++u) {
                int sidx = sb + u;
                if (sidx < Q) {               // uniform guard
                    float pv = predT[(jtop - sidx) * CB + c];  // pad rows = 0
#pragma unroll
                    for (int k = 0; k < 16; ++k)
                        acc[k] += pv * cf[(u + k) & 15];
                    cf[u] = funion[(bidx + 16 + sidx) * CB + c];  // row <= 150
                }
            }
        }
#pragma unroll
        for (int k = 0; k < 16; ++k) {        // fold 4 quarters (free)
            acc[k] += __shfl_xor(acc[k], 16, 64);
            acc[k] += __shfl_xor(acc[k], 32, 64);
        }
        // lane owns rows k = 4q + r (register-array select must be static)
#pragma unroll
        for (int r = 0; r < 4; ++r) {
            float av = (q == 0) ? acc[r] : (q == 1) ? acc[4 + r]
                     : (q == 2) ? acc[8 + r] : acc[12 + r];
            int i = i0 + (q << 2) + r;
            if (i < N2) {
                float diff = av - dgv[r];
                lsum += diff * diff;
            }
        }
    }

    // ---- loss reduction ----
#pragma unroll
    for (int off = 32; off > 0; off >>= 1)
        lsum += __shfl_down(lsum, off, 64);
    if ((t & 63) == 0) lred[w] = lsum;
    __syncthreads();
    if (t == 0)
        atomicAdd(out, (lred[0] + lred[1] + lred[2] + lred[3]) *
                       (1.0f / ((float)N2 * (float)MM)));
}

extern "C" void kernel_launch(void* const* d_in, const int* in_sizes, int n_in,
                              void* d_out, int out_size, void* d_ws, size_t ws_size,
                              hipStream_t stream) {
    const float* rt   = (const float*)d_in[0];
    const float* dgt  = (const float*)d_in[1];
    const float* si   = (const float*)d_in[2];
    const float* f    = (const float*)d_in[3];
    const float* seed = (const float*)d_in[4];

    hipMemsetAsync(d_out, 0, sizeof(float), stream);
    npi_fused<<<dim3(MM / CB), dim3(BT), 0, stream>>>(
        rt, dgt, si, f, seed, (float*)d_out);
}

// Round 9
// 104.947 us; speedup vs baseline: 1.4049x; 1.4049x over previous
//
#include <hip/hip_runtime.h>

#define N2 128
#define MM 16384
#define START 6
#define CB 32        // columns per block -> 512 blocks
#define BT 256       // 4 waves = 8 half-wave shares (32 lanes each)
#define PROWS 132    // predT rows: 0..127 data, 128..131 zero
#define FROWS 152    // fTd rows: index = 16 + d; zero outside d in [2,127]

__global__ __launch_bounds__(BT, 2) void npi_fused(
    const float* __restrict__ rt, const float* __restrict__ dgt,
    const float* __restrict__ si, const float* __restrict__ f,
    const float* __restrict__ seed, float* __restrict__ out)
{
    __shared__ float predT[PROWS * CB];    // 16.5 KiB [row][col]
    __shared__ float funion[FROWS * CB];   // 19.0 KiB: part+hrow (phase 1) / fTd (phase 2)
    __shared__ float si_s[N2];
    __shared__ float lred[4];
    float* part = funion;                  // [wave][k][col], floats [0, 2048)
    float* hrow = funion + 2048;           // [k][col], floats [2048, 2560)
    float* fTd  = funion;                  // staged after phase 1

    const int t = threadIdx.x;
    const int c = t & (CB - 1);
    const int w = t >> 6;          // wave 0..3
    const int g = t >> 5;          // half-wave share 0..7
    const int hw = g & 1;          // half within wave
    const int m = blockIdx.x * CB + c;

    // f rows for this share -> registers; loads stream under all of phase 1.
    float fregs[16];
#pragma unroll
    for (int q = 0; q < 16; ++q)
        fregs[q] = f[((g << 4) + q) * MM + m];

    if (t < N2) si_s[t] = si[t];
    if (g < START) predT[(g << 5) + c] = seed[g * MM + m];
    if (g < 4) predT[((128 + g) << 5) + c] = 0.f;   // pred pad rows 128..131

    float r16v[16];
#pragma unroll
    for (int k = 0; k < 16; ++k)
        r16v[k] = rt[k * MM + m];                   // chunk-0 rows

    __syncthreads();

    float sr[16];
#pragma unroll
    for (int k = 1; k < 16; ++k) sr[k] = si_s[k];

    // ---- phase 1, chunk 0: short-chain triangle from seeds (redundant) ----
    {
        float p_[16], v[16];
#pragma unroll
        for (int k = 0; k < 16; ++k) p_[k] = 0.f;
#pragma unroll
        for (int k = 0; k < 16; ++k) {
            float vk;
            if (k < START) vk = predT[(k << 5) + c];
            else vk = r16v[k] * (p_[k] + sr[1] * v[k - 1]);
            v[k] = vk;
#pragma unroll
            for (int k2 = k + 2; k2 < 16; ++k2)
                p_[k2] += sr[k2 - k] * vk;
        }
        if (w == 3 && hw == 0) {
#pragma unroll
            for (int k = START; k < 16; ++k) predT[(k << 5) + c] = v[k];
        }
    }
    __syncthreads();

    // ---- phase 1, chunks b = 1..7: 8 equal j-shares of 2b each ----
    for (int b = 1; b < 8; ++b) {
        const int i0 = b << 4;
        const int nst = b << 1;                   // steps per share (<= 14)
#pragma unroll
        for (int k = 0; k < 16; ++k)
            r16v[k] = rt[(i0 + k) * MM + m];      // prefetch for triangle

        const int jhi = nst * (g + 1);            // share j in [jhi-nst, jhi)
        const int base = i0 - jhi + 1;            // >= 1
        float c16[16];
#pragma unroll
        for (int e = 0; e < 16; ++e) c16[e] = si_s[base + e];
        float acc[16];
#pragma unroll
        for (int k = 0; k < 16; ++k) acc[k] = 0.f;
#pragma unroll
        for (int u = 0; u < 14; ++u) {            // nst <= 14; uniform guard
            if (u < nst) {
                float p = predT[((jhi - 1 - u) << 5) + c];
#pragma unroll
                for (int k = 0; k < 16; ++k)
                    acc[k] += p * c16[(u + k) & 15];
                if (u + 1 < nst) c16[u & 15] = si_s[base + 16 + u];  // <=127
            }
        }
        // fold the two shares of each wave (free, in-register)
#pragma unroll
        for (int k = 0; k < 16; ++k)
            acc[k] += __shfl_xor(acc[k], 32, 64);
        if (hw == 0) {
#pragma unroll
            for (int k = 0; k < 16; ++k)
                part[(((w << 4) + k) << 5) + c] = acc[k];
        }
        __syncthreads();

        // stage B: distributed reduce — 8 reads + 2 writes per thread
        {
            const int k2 = t >> 5;                // 0..7
            float sA = 0.f, sB = 0.f;
#pragma unroll
            for (int ww = 0; ww < 4; ++ww) {
                sA += part[(((ww << 4) + k2) << 5) + c];
                sB += part[(((ww << 4) + k2 + 8) << 5) + c];
            }
            hrow[(k2 << 5) + c] = sA;
            hrow[((k2 + 8) << 5) + c] = sB;
        }
        __syncthreads();

        // short-chain triangle (redundant per wave; hrow reads broadcast)
        float p_[16], v[16];
#pragma unroll
        for (int k = 0; k < 16; ++k)
            p_[k] = hrow[(k << 5) + c];
#pragma unroll
        for (int k = 0; k < 16; ++k) {
            float vk = (k == 0) ? (r16v[0] * p_[0])
                                : (r16v[k] * (p_[k] + sr[1] * v[k - 1]));
            v[k] = vk;
#pragma unroll
            for (int k2 = k + 2; k2 < 16; ++k2)
                p_[k2] += sr[k2 - k] * vk;
        }
        // wave w writes rows [i0+4w, i0+4w+4), 2 rows per half-wave
        {
            float a0, a1;
            if (w == 0)      { a0 = hw ? v[2]  : v[0];  a1 = hw ? v[3]  : v[1];  }
            else if (w == 1) { a0 = hw ? v[6]  : v[4];  a1 = hw ? v[7]  : v[5];  }
            else if (w == 2) { a0 = hw ? v[10] : v[8];  a1 = hw ? v[11] : v[9];  }
            else             { a0 = hw ? v[14] : v[12]; a1 = hw ? v[15] : v[13]; }
            const int r0 = i0 + (w << 2) + (hw << 1);
            predT[(r0 << 5) + c] = a0;
            predT[((r0 + 1) << 5) + c] = a1;
        }
        __syncthreads();
    }

    // ---- stage f -> fTd (part/hrow dead now); zero the pad rows too ----
#pragma unroll
    for (int q = 0; q < 16; ++q) {
        int d = (g << 4) + q;
        fTd[((16 + d) << 5) + c] = (d < 2) ? 0.f : fregs[q];
    }
    fTd[((g << 1) << 5) + c] = 0.f;               // rows 0..15 (2 per share)
    fTd[(((g << 1) + 1) << 5) + c] = 0.f;
    fTd[((144 + g) << 5) + c] = 0.f;              // rows 144..151
    __syncthreads();

    // ---- phase 2: deaths conv + MSE ----
    float lsum = 0.f;
    if (hw == 0) {
        float dv = dgt[w * MM + m];
        float e0 = (w == 0) ? (1e-9f - dv) : dv;
        lsum += e0 * e0;
        if (w < 2) {
            float d2 = dgt[(4 + w) * MM + m];
            lsum += d2 * d2;
        }
    }

#pragma unroll
    for (int pass = 0; pass < 2; ++pass) {
        const int n = pass ? (7 - w) : w;         // pairs {n, 7-n}: balanced
        const int i0 = START + (n << 4);          // 6..118
        const int jhi2 = i0 + 14;                 // even
        const int steps = jhi2 >> 1;              // equal per half (<= 66)
        const int jh = hw ? jhi2 : (jhi2 >> 1);   // this half's j-range top
        const int fb = 17 + i0 - jh;              // ring base index into fTd

        float dg[16];
#pragma unroll
        for (int k = 0; k < 16; ++k)
            dg[k] = (i0 + k < N2) ? dgt[(i0 + k) * MM + m] : 0.f;

        float cf[16];
#pragma unroll
        for (int e = 0; e < 16; ++e) cf[e] = fTd[((fb + e) << 5) + c];
        float acc[16];
#pragma unroll
        for (int k = 0; k < 16; ++k) acc[k] = 0.f;

        for (int sb = 0; sb < steps; sb += 16) {
#pragma unroll
            for (int u = 0; u < 16; ++u) {
                int s = sb + u;
                if (s < steps) {                  // uniform guard
                    float p = predT[((jh - 1 - s) << 5) + c];  // pad rows = 0
#pragma unroll
                    for (int k = 0; k < 16; ++k)
                        acc[k] += p * cf[(u + k) & 15];
                    cf[u] = fTd[((fb + 16 + s) << 5) + c];     // max idx 150
                }
            }
        }
#pragma unroll
        for (int k = 0; k < 16; ++k)
            acc[k] += __shfl_xor(acc[k], 32, 64);
        if (hw == 0) {
#pragma unroll
            for (int k = 0; k < 16; ++k) {
                if (i0 + k < N2) {
                    float diff = acc[k] - dg[k];
                    lsum += diff * diff;
                }
            }
        }
    }

    // ---- loss reduction ----
#pragma unroll
    for (int off = 32; off > 0; off >>= 1)
        lsum += __shfl_down(lsum, off, 64);
    if ((t & 63) == 0) lred[w] = lsum;
    __syncthreads();
    if (t == 0)
        atomicAdd(out, (lred[0] + lred[1] + lred[2] + lred[3]) *
                       (1.0f / ((float)N2 * (float)MM)));
}

extern "C" void kernel_launch(void* const* d_in, const int* in_sizes, int n_in,
                              void* d_out, int out_size, void* d_ws, size_t ws_size,
                              hipStream_t stream) {
    const float* rt   = (const float*)d_in[0];
    const float* dgt  = (const float*)d_in[1];
    const float* si   = (const float*)d_in[2];
    const float* f    = (const float*)d_in[3];
    const float* seed = (const float*)d_in[4];

    hipMemsetAsync(d_out, 0, sizeof(float), stream);
    npi_fused<<<dim3(MM / CB), dim3(BT), 0, stream>>>(
        rt, dgt, si, f, seed, (float*)d_out);
}

// Round 10
// 97.846 us; speedup vs baseline: 1.5068x; 1.0726x over previous
//
#include <hip/hip_runtime.h>

#define N2 128
#define MM 16384
#define START 6
#define CB 32        // columns per block -> 512 blocks
#define BT 256       // 4 waves; 8 shares of 32 lanes; share g owns row-groups {g, 15-g}
#define FSTR 143     // fC stride (odd => conflict-free col-major); idx = 15 + d, d in [-15,127]

__global__ __launch_bounds__(BT, 2) void npi_fused(
    const float* __restrict__ rt, const float* __restrict__ dgt,
    const float* __restrict__ si, const float* __restrict__ f,
    const float* __restrict__ seed, float* __restrict__ out)
{
    __shared__ float fC[CB * FSTR];    // 17.9 KiB  [c][15+d], zero for d<2
    __shared__ float hrow[16 * CB];    //  2.0 KiB  published H for current chunk
    __shared__ float si_s[N2];
    __shared__ float lred[4];

    const int t = threadIdx.x;
    const int c = t & 31;
    const int g = t >> 5;          // share 0..7
    const int w = t >> 6;
    const int m = blockIdx.x * CB + c;

    // ---- global loads (all fired early; latency hidden under staging) ----
    float fregs[16];
#pragma unroll
    for (int q = 0; q < 16; ++q)
        fregs[q] = f[((g << 4) + q) * MM + m];
    float sd[START];
#pragma unroll
    for (int k = 0; k < START; ++k) sd[k] = seed[k * MM + m];
    float rtv[16];
#pragma unroll
    for (int k = 0; k < 16; ++k) rtv[k] = rt[k * MM + m];
    float dgv[2][8];
#pragma unroll
    for (int pass = 0; pass < 2; ++pass) {
        const int gi = pass ? (15 - g) : g;
#pragma unroll
        for (int r = 0; r < 8; ++r)
            dgv[pass][r] = dgt[((gi << 3) + r) * MM + m];
    }

    // ---- stage si + f (col-major, zero-padded d<2 and d<0) ----
    if (t < N2) si_s[t] = si[t];
#pragma unroll
    for (int z = 0; z < 2; ++z) {
        int p = t + z * BT;
        if (p < 15 * CB) fC[(p & 31) * FSTR + (p >> 5)] = 0.f;  // idx 0..14 (d<0)
    }
#pragma unroll
    for (int q = 0; q < 16; ++q) {
        int d = (g << 4) + q;
        fC[c * FSTR + 15 + d] = (d < 2) ? 0.f : fregs[q];
    }
    __syncthreads();

    float sr[16];
#pragma unroll
    for (int k = 1; k < 16; ++k) sr[k] = si_s[k];

    float Hacc[2][8], Eacc[2][8];
#pragma unroll
    for (int pass = 0; pass < 2; ++pass)
#pragma unroll
        for (int r = 0; r < 8; ++r) { Hacc[pass][r] = 0.f; Eacc[pass][r] = 0.f; }

    float v[16], rtn[16];

    // ================= chunk 0 =================
    {
        float p_[16];
#pragma unroll
        for (int k = 0; k < 16; ++k) p_[k] = 0.f;
#pragma unroll
        for (int k = 0; k < 16; ++k) {
            float vk;
            if (k < START) vk = sd[k];
            else vk = rtv[k] * (p_[k] + sr[1] * v[k - 1]);
            v[k] = vk;
#pragma unroll
            for (int k2 = k + 2; k2 < 16; ++k2)
                p_[k2] += sr[k2 - k] * vk;
        }
    }
#pragma unroll
    for (int k = 0; k < 16; ++k) rtn[k] = rt[(16 + k) * MM + m];  // prefetch
#pragma unroll
    for (int pass = 0; pass < 2; ++pass) {
        const int gi = pass ? (15 - g) : g;
        if (gi >= 2) {                         // H: strictly future rows
            const int off = (gi << 3) - 15;    // >= 1
            float sw[23];
#pragma unroll
            for (int e = 0; e < 23; ++e) sw[e] = si_s[off + e];
#pragma unroll
            for (int r = 0; r < 8; ++r)
#pragma unroll
                for (int k = 0; k < 16; ++k)
                    Hacc[pass][r] += v[k] * sw[15 + r - k];
        }
        {                                      // E: all groups (zero-pad handles d<2)
            const int offE = (gi << 3);
            float fw[23];
#pragma unroll
            for (int e = 0; e < 23; ++e) fw[e] = fC[c * FSTR + offE + e];
#pragma unroll
            for (int r = 0; r < 8; ++r)
#pragma unroll
                for (int k = 0; k < 16; ++k)
                    Eacc[pass][r] += v[k] * fw[15 + r - k];
        }
    }
#pragma unroll
    for (int k = 0; k < 16; ++k) rtv[k] = rtn[k];
    __syncthreads();

    // ================= chunks 1..7 =================
    for (int cb = 1; cb < 8; ++cb) {
        // owners publish this chunk's H
#pragma unroll
        for (int pass = 0; pass < 2; ++pass) {
            const int gi = pass ? (15 - g) : g;
            if ((gi >> 1) == cb) {
#pragma unroll
                for (int r = 0; r < 8; ++r)
                    hrow[((((gi & 1) << 3) + r) << 5) + c] = Hacc[pass][r];
            }
        }
        __syncthreads();

        // triangle (redundant per lane; short dependence chain)
        float p_[16];
#pragma unroll
        for (int k = 0; k < 16; ++k) p_[k] = hrow[(k << 5) + c];
#pragma unroll
        for (int k = 0; k < 16; ++k) {
            float vk = (k == 0) ? (rtv[0] * p_[0])
                                : (rtv[k] * (p_[k] + sr[1] * v[k - 1]));
            v[k] = vk;
#pragma unroll
            for (int k2 = k + 2; k2 < 16; ++k2)
                p_[k2] += sr[k2 - k] * vk;
        }
        if (cb < 7) {
#pragma unroll
            for (int k = 0; k < 16; ++k)
                rtn[k] = rt[(((cb + 1) << 4) + k) * MM + m];
        }

        // accumulate H/E contributions of this chunk into owned rows
#pragma unroll
        for (int pass = 0; pass < 2; ++pass) {
            const int gi = pass ? (15 - g) : g;
            if (gi >= 2 * cb + 2) {
                const int off = (gi << 3) - (cb << 4) - 15;   // >= 1
                float sw[23];
#pragma unroll
                for (int e = 0; e < 23; ++e) sw[e] = si_s[off + e];
#pragma unroll
                for (int r = 0; r < 8; ++r)
#pragma unroll
                    for (int k = 0; k < 16; ++k)
                        Hacc[pass][r] += v[k] * sw[15 + r - k];
            }
            if (gi >= 2 * cb) {
                const int offE = (gi << 3) - (cb << 4);       // >= 0
                float fw[23];
#pragma unroll
                for (int e = 0; e < 23; ++e) fw[e] = fC[c * FSTR + offE + e];
#pragma unroll
                for (int r = 0; r < 8; ++r)
#pragma unroll
                    for (int k = 0; k < 16; ++k)
                        Eacc[pass][r] += v[k] * fw[15 + r - k];
            }
        }
#pragma unroll
        for (int k = 0; k < 16; ++k) rtv[k] = rtn[k];
        __syncthreads();
    }

    // ---- loss ----
    float lsum = 0.f;
#pragma unroll
    for (int pass = 0; pass < 2; ++pass) {
        const int gi = pass ? (15 - g) : g;
#pragma unroll
        for (int r = 0; r < 8; ++r) {
            const int i = (gi << 3) + r;
            float e = Eacc[pass][r];
            if (i == 0) e = 1e-9f;
            else if (i < START) e = 0.f;
            float diff = e - dgv[pass][r];
            lsum += diff * diff;
        }
    }
#pragma unroll
    for (int off = 32; off > 0; off >>= 1)
        lsum += __shfl_down(lsum, off, 64);
    if ((t & 63) == 0) lred[w] = lsum;
    __syncthreads();
    if (t == 0)
        atomicAdd(out, (lred[0] + lred[1] + lred[2] + lred[3]) *
                       (1.0f / ((float)N2 * (float)MM)));
}

extern "C" void kernel_launch(void* const* d_in, const int* in_sizes, int n_in,
                              void* d_out, int out_size, void* d_ws, size_t ws_size,
                              hipStream_t stream) {
    const float* rt   = (const float*)d_in[0];
    const float* dgt  = (const float*)d_in[1];
    const float* si   = (const float*)d_in[2];
    const float* f    = (const float*)d_in[3];
    const float* seed = (const float*)d_in[4];

    hipMemsetAsync(d_out, 0, sizeof(float), stream);
    npi_fused<<<dim3(MM / CB), dim3(BT), 0, stream>>>(
        rt, dgt, si, f, seed, (float*)d_out);
}